// Round 6
// baseline (242.004 us; speedup 1.0000x reference)
//
#include <hip/hip_runtime.h>
#include <hip/hip_bf16.h>

// GPT-2 attention block. Inputs/outputs fp32; internal bf16 MFMA, fp32 accum.
// B=4, S=1024, D=1024, H=16, hd=64.
//
// R6: attention uses direct-exp softmax (shift-invariant; scores bounded) ->
//     no per-tile cross-lane chain, no alpha rescale. Split-K units (256-key
//     chunks) write additive partials (bf16 O, fp32 l) reduced by a second
//     kernel -> ~uniform work, 2.5x more waves. Host falls back to a
//     single-pass barrier-free kernel if ws_size is too small.

typedef __bf16 bf16x8 __attribute__((ext_vector_type(8)));
typedef __bf16 bf16x4 __attribute__((ext_vector_type(4)));
typedef float f32x4 __attribute__((ext_vector_type(4)));

__device__ __forceinline__ void load_lds16(const void* g, void* l) {
  __builtin_amdgcn_global_load_lds(
      (const __attribute__((address_space(1))) void*)g,
      (__attribute__((address_space(3))) void*)l, 16, 0, 0);
}

// ---------------- convert fp32 -> bf16 ----------------
__global__ __launch_bounds__(256) void f32_to_bf16(
    const float* __restrict__ in, __bf16* __restrict__ out, int n) {
  int i = (blockIdx.x * 256 + threadIdx.x) * 4;
  if (i + 3 < n) {
    float4 v = *(const float4*)(in + i);
    out[i + 0] = (__bf16)v.x;
    out[i + 1] = (__bf16)v.y;
    out[i + 2] = (__bf16)v.z;
    out[i + 3] = (__bf16)v.w;
  }
}

// ---------------- convert+transpose: WT[n*K+k] = (bf16)W[k*N+n] ----------------
__global__ __launch_bounds__(256) void transpose_f32_bf16(
    const float* __restrict__ W, __bf16* __restrict__ WT, int K, int N) {
  __shared__ __bf16 tile[32][33];
  int n0 = blockIdx.x * 32, k0 = blockIdx.y * 32;
  int tx = threadIdx.x, ty = threadIdx.y;  // block (32,8)
#pragma unroll
  for (int j = 0; j < 32; j += 8)
    tile[ty + j][tx] = (__bf16)W[(size_t)(k0 + ty + j) * N + n0 + tx];
  __syncthreads();
#pragma unroll
  for (int j = 0; j < 32; j += 8)
    WT[(size_t)(n0 + ty + j) * K + k0 + tx] = tile[tx][ty + j];
}

// ---------------- V transpose: VT[bh][d][s] from QKV ----------------
__global__ __launch_bounds__(256) void transpose_v(
    const __bf16* __restrict__ qkv, __bf16* __restrict__ VT) {
  const int lane = threadIdx.x & 63, wave = threadIdx.x >> 6;
  const int bh = blockIdx.x >> 4;
  const int kb = (blockIdx.x & 15) * 64;
  const int b = bh >> 4, h = bh & 15;
  const __bf16* src =
      qkv + ((size_t)b * 1024 + kb + lane) * 3072 + 2048 + h * 64 + wave * 16;
  bf16x8 v0 = *(const bf16x8*)src;
  bf16x8 v1 = *(const bf16x8*)(src + 8);
  __bf16* dst = VT + ((size_t)bh * 64 + wave * 16) * 1024 + kb + lane;
#pragma unroll
  for (int i = 0; i < 8; ++i) {
    dst[(size_t)i * 1024] = v0[i];
    dst[(size_t)(i + 8) * 1024] = v1[i];
  }
}

// ---------------- GEMM (m97 structure): C = A @ BT^T + bias ----------------
template <typename OutT>
__global__ __launch_bounds__(256) void gemm_bt_bias(
    const __bf16* __restrict__ A, const __bf16* __restrict__ BT,
    const float* __restrict__ bias, OutT* __restrict__ C, int M, int N, int K) {
  __shared__ __bf16 sA[128 * 32];
  __shared__ __bf16 sB[128 * 32];

  const int tid = threadIdx.x;
  const int lane = tid & 63;
  const int wave = tid >> 6;
  const int waveM = wave >> 1, waveN = wave & 1;
  const int quad = lane >> 4;
  const int l16 = lane & 15;
  const int rowBase = blockIdx.y * 128;
  const int colBase = blockIdx.x * 128;

  const int rIn = lane >> 2;
  const int sIn = lane & 3;
  const int gc = sIn ^ (rIn & 3) ^ ((rIn >> 2) & 3);
  const int readSlot = quad ^ (l16 & 3) ^ ((l16 >> 2) & 3);

  f32x4 acc[4][4] = {};

  for (int k0 = 0; k0 < K; k0 += 32) {
    __syncthreads();
#pragma unroll
    for (int j = 0; j < 2; ++j) {
      const int rb = wave * 32 + j * 16;
      load_lds16(&A[(size_t)(rowBase + rb + rIn) * K + k0 + gc * 8], &sA[rb * 32]);
      load_lds16(&BT[(size_t)(colBase + rb + rIn) * K + k0 + gc * 8], &sB[rb * 32]);
    }
    __syncthreads();

    bf16x8 af[4], bfr[4];
#pragma unroll
    for (int mt = 0; mt < 4; ++mt)
      af[mt] = *(const bf16x8*)(&sA[(waveM * 64 + mt * 16 + l16) * 32 + readSlot * 8]);
#pragma unroll
    for (int nt = 0; nt < 4; ++nt)
      bfr[nt] = *(const bf16x8*)(&sB[(waveN * 64 + nt * 16 + l16) * 32 + readSlot * 8]);
#pragma unroll
    for (int mt = 0; mt < 4; ++mt)
#pragma unroll
      for (int nt = 0; nt < 4; ++nt)
        acc[mt][nt] = __builtin_amdgcn_mfma_f32_16x16x32_bf16(
            af[mt], bfr[nt], acc[mt][nt], 0, 0, 0);
  }

#pragma unroll
  for (int mt = 0; mt < 4; ++mt) {
    int row = rowBase + waveM * 64 + mt * 16 + quad * 4;
#pragma unroll
    for (int nt = 0; nt < 4; ++nt) {
      int col = colBase + waveN * 64 + nt * 16 + l16;
      float bv = bias[col];
#pragma unroll
      for (int r = 0; r < 4; ++r)
        C[(size_t)(row + r) * N + col] = (OutT)(acc[mt][nt][r] + bv);
    }
  }
}

// ---------------- split-K flash attention unit ----------------
// Unit = (bh, 16-q-tile qt, 256-key chunk u). Direct-exp softmax (additive
// partials). Writes Opart[slot][q][d] (bf16) and Lpart[slot][q] (fp32).
// slot == blockIdx.x by the within-bh enumeration (160 units per bh).
__global__ __launch_bounds__(64) void attn_split(
    const __bf16* __restrict__ qkv, const __bf16* __restrict__ VT,
    __bf16* __restrict__ Opart, float* __restrict__ Lpart) {
  __shared__ __bf16 pw[16 * 64];  // wave-private P buffer

  const int lane = threadIdx.x;
  const int quad = lane >> 4;
  const int l16 = lane & 15;

  const int bh = blockIdx.x / 160;
  const int w = blockIdx.x - bh * 160;
  int qt, u;
  if (w < 16) { qt = w; u = 0; }
  else if (w < 48) { int t = w - 16; qt = 16 + (t >> 1); u = t & 1; }
  else if (w < 96) { int t = w - 48; int q3 = t / 3; qt = 32 + q3; u = t - 3 * q3; }
  else { int t = w - 96; qt = 48 + (t >> 2); u = t & 3; }
  const int slot = blockIdx.x;
  const int b = bh >> 4, h = bh & 15;
  const int qb = qt * 16;
  const int tot = (qt >> 2) + 1;          // total 64-key tiles for this q-tile
  const int ntile = min(4, tot - u * 4);  // tiles in this unit (>=1)
  const int lastg = tot - 1;              // global index of diagonal tile

  const size_t rowS = 3072;
  const __bf16* Qb = qkv + (size_t)b * 1024 * rowS + h * 64;
  const __bf16* Kb = Qb + 1024;
  const __bf16* VTb = VT + (size_t)bh * 64 * 1024;

  bf16x8 qA0, qA1;
  {
    const __bf16* qr = Qb + (size_t)(qb + l16) * rowS + quad * 8;
    qA0 = *(const bf16x8*)qr;
    qA1 = *(const bf16x8*)(qr + 32);
  }

  f32x4 Oacc[4] = {};
  float psum[4] = {0.f, 0.f, 0.f, 0.f};
  const int swq = l16 & 7;

  for (int t = 0; t < ntile; ++t) {
    const int kb = u * 256 + t * 64;

    // K B-fragments, direct global b128
    bf16x8 kB0[4], kB1[4];
#pragma unroll
    for (int n = 0; n < 4; ++n) {
      const __bf16* kr = Kb + (size_t)(kb + n * 16 + l16) * rowS + quad * 8;
      kB0[n] = *(const bf16x8*)kr;
      kB1[n] = *(const bf16x8*)(kr + 32);
    }
    // V B-fragments (in flight during QK/exp)
    bf16x8 vB0[4], vB1[4];
#pragma unroll
    for (int nt = 0; nt < 4; ++nt) {
      const __bf16* vr = VTb + (size_t)(nt * 16 + l16) * 1024 + kb + quad * 8;
      vB0[nt] = *(const bf16x8*)vr;
      vB1[nt] = *(const bf16x8*)(vr + 32);
    }

    // QK^T
    float sc[4][4];
#pragma unroll
    for (int n = 0; n < 4; ++n) {
      f32x4 c = {};
      c = __builtin_amdgcn_mfma_f32_16x16x32_bf16(qA0, kB0[n], c, 0, 0, 0);
      c = __builtin_amdgcn_mfma_f32_16x16x32_bf16(qA1, kB1[n], c, 0, 0, 0);
#pragma unroll
      for (int r = 0; r < 4; ++r) sc[n][r] = c[r] * 0.125f;
    }

    // causal mask (only the tile containing the diagonal)
    if (u * 4 + t == lastg) {
#pragma unroll
      for (int n = 0; n < 4; ++n) {
        const int kg = kb + n * 16 + l16;
#pragma unroll
        for (int r = 0; r < 4; ++r)
          if (kg > qb + quad * 4 + r) sc[n][r] = -1.0e30f;  // exp -> exact 0
      }
    }

    // direct exp (shift-free; scores bounded, clamp is inactive insurance)
#pragma unroll
    for (int n = 0; n < 4; ++n)
#pragma unroll
      for (int r = 0; r < 4; ++r) {
        float p = __expf(fminf(sc[n][r], 60.0f));
        sc[n][r] = p;
        psum[r] += p;
      }

    // P: C-layout -> wave-private LDS (swizzled) -> A-fragments
    {
      const int kb8 = l16 >> 3, lo = l16 & 7;
#pragma unroll
      for (int n = 0; n < 4; ++n) {
        const int chunk = n * 2 + kb8;
#pragma unroll
        for (int r = 0; r < 4; ++r) {
          const int q = quad * 4 + r;
          pw[q * 64 + ((chunk ^ (q & 7)) << 3) + lo] = (__bf16)sc[n][r];
        }
      }
    }

    bf16x8 pA0 = *(const bf16x8*)(&pw[l16 * 64 + ((quad ^ swq) << 3)]);
    bf16x8 pA1 = *(const bf16x8*)(&pw[l16 * 64 + (((quad + 4) ^ swq) << 3)]);
#pragma unroll
    for (int nt = 0; nt < 4; ++nt) {
      Oacc[nt] = __builtin_amdgcn_mfma_f32_16x16x32_bf16(pA0, vB0[nt], Oacc[nt], 0, 0, 0);
      Oacc[nt] = __builtin_amdgcn_mfma_f32_16x16x32_bf16(pA1, vB1[nt], Oacc[nt], 0, 0, 0);
    }
  }

  // row sums: reduce per-lane partials across the 16 lanes of each quad group
  float l_row[4];
#pragma unroll
  for (int r = 0; r < 4; ++r) {
    float ps = psum[r];
    ps += __shfl_xor(ps, 1);
    ps += __shfl_xor(ps, 2);
    ps += __shfl_xor(ps, 4);
    ps += __shfl_xor(ps, 8);
    l_row[r] = ps;
  }
  if (l16 == 0) {
#pragma unroll
    for (int r = 0; r < 4; ++r)
      Lpart[(size_t)slot * 16 + quad * 4 + r] = l_row[r];
  }
#pragma unroll
  for (int nt = 0; nt < 4; ++nt)
#pragma unroll
    for (int r = 0; r < 4; ++r)
      Opart[(size_t)slot * 1024 + (quad * 4 + r) * 64 + nt * 16 + l16] =
          (__bf16)Oacc[nt][r];
}

// ---------------- split-K reduce: sum partials, normalize, write Aattn ----------------
__global__ __launch_bounds__(256) void attn_reduce(
    const __bf16* __restrict__ Opart, const float* __restrict__ Lpart,
    __bf16* __restrict__ Aout) {
  const int blk = blockIdx.x;  // bh*64 + qt
  const int bh = blk >> 6, qt = blk & 63;
  const int b = bh >> 4, h = bh & 15;
  const int g = qt >> 4;
  int wBase;
  if (g == 0) wBase = qt;
  else if (g == 1) wBase = 16 + (qt - 16) * 2;
  else if (g == 2) wBase = 48 + (qt - 32) * 3;
  else wBase = 96 + (qt - 48) * 4;
  const int slot0 = bh * 160 + wBase;
  const int nu = g + 1;

  const int tid = threadIdx.x;
  const int qr = tid >> 4;         // 4 elems per thread, all in row qr
  const int d0 = (tid & 15) * 4;

  float l = 0.f;
  for (int uu = 0; uu < nu; ++uu) l += Lpart[(size_t)(slot0 + uu) * 16 + qr];
  float o[4] = {0.f, 0.f, 0.f, 0.f};
  for (int uu = 0; uu < nu; ++uu) {
    bf16x4 v = *(const bf16x4*)(Opart + (size_t)(slot0 + uu) * 1024 + qr * 64 + d0);
#pragma unroll
    for (int i = 0; i < 4; ++i) o[i] += (float)v[i];
  }
  const float inv = 1.0f / l;
  bf16x4 res;
#pragma unroll
  for (int i = 0; i < 4; ++i) res[i] = (__bf16)(o[i] * inv);
  *(bf16x4*)(Aout + ((size_t)b * 1024 + qt * 16 + qr) * 1024 + h * 64 + d0) = res;
}

// ---------------- fallback: single-pass barrier-free attention (direct exp) ----------------
__global__ __launch_bounds__(64) void attn_mfma(
    const __bf16* __restrict__ qkv, const __bf16* __restrict__ VT,
    __bf16* __restrict__ Aout) {
  __shared__ __bf16 pw[16 * 64];

  const int lane = threadIdx.x;
  const int quad = lane >> 4;
  const int l16 = lane & 15;

  const int bh = blockIdx.x & 63;
  const int qw = 63 - (blockIdx.x >> 6);  // heaviest first
  const int b = bh >> 4, h = bh & 15;
  const int qb = qw * 16;

  const size_t rowS = 3072;
  const __bf16* Qb = qkv + (size_t)b * 1024 * rowS + h * 64;
  const __bf16* Kb = Qb + 1024;
  const __bf16* VTb = VT + (size_t)bh * 64 * 1024;

  bf16x8 qA0, qA1;
  {
    const __bf16* qr = Qb + (size_t)(qb + l16) * rowS + quad * 8;
    qA0 = *(const bf16x8*)qr;
    qA1 = *(const bf16x8*)(qr + 32);
  }

  f32x4 Oacc[4] = {};
  float psum[4] = {0.f, 0.f, 0.f, 0.f};
  const int swq = l16 & 7;
  const int ktiles = (qb >> 6) + 1;

  for (int kt = 0; kt < ktiles; ++kt) {
    const int kb = kt * 64;

    bf16x8 kB0[4], kB1[4];
#pragma unroll
    for (int n = 0; n < 4; ++n) {
      const __bf16* kr = Kb + (size_t)(kb + n * 16 + l16) * rowS + quad * 8;
      kB0[n] = *(const bf16x8*)kr;
      kB1[n] = *(const bf16x8*)(kr + 32);
    }
    bf16x8 vB0[4], vB1[4];
#pragma unroll
    for (int nt = 0; nt < 4; ++nt) {
      const __bf16* vr = VTb + (size_t)(nt * 16 + l16) * 1024 + kb + quad * 8;
      vB0[nt] = *(const bf16x8*)vr;
      vB1[nt] = *(const bf16x8*)(vr + 32);
    }

    float sc[4][4];
#pragma unroll
    for (int n = 0; n < 4; ++n) {
      f32x4 c = {};
      c = __builtin_amdgcn_mfma_f32_16x16x32_bf16(qA0, kB0[n], c, 0, 0, 0);
      c = __builtin_amdgcn_mfma_f32_16x16x32_bf16(qA1, kB1[n], c, 0, 0, 0);
#pragma unroll
      for (int r = 0; r < 4; ++r) sc[n][r] = c[r] * 0.125f;
    }
    if (kt == ktiles - 1) {
#pragma unroll
      for (int n = 0; n < 4; ++n) {
        const int kg = kb + n * 16 + l16;
#pragma unroll
        for (int r = 0; r < 4; ++r)
          if (kg > qb + quad * 4 + r) sc[n][r] = -1.0e30f;
      }
    }
#pragma unroll
    for (int n = 0; n < 4; ++n)
#pragma unroll
      for (int r = 0; r < 4; ++r) {
        float p = __expf(fminf(sc[n][r], 60.0f));
        sc[n][r] = p;
        psum[r] += p;
      }

    {
      const int kb8 = l16 >> 3, lo = l16 & 7;
#pragma unroll
      for (int n = 0; n < 4; ++n) {
        const int chunk = n * 2 + kb8;
#pragma unroll
        for (int r = 0; r < 4; ++r) {
          const int q = quad * 4 + r;
          pw[q * 64 + ((chunk ^ (q & 7)) << 3) + lo] = (__bf16)sc[n][r];
        }
      }
    }

    bf16x8 pA0 = *(const bf16x8*)(&pw[l16 * 64 + ((quad ^ swq) << 3)]);
    bf16x8 pA1 = *(const bf16x8*)(&pw[l16 * 64 + (((quad + 4) ^ swq) << 3)]);
#pragma unroll
    for (int nt = 0; nt < 4; ++nt) {
      Oacc[nt] = __builtin_amdgcn_mfma_f32_16x16x32_bf16(pA0, vB0[nt], Oacc[nt], 0, 0, 0);
      Oacc[nt] = __builtin_amdgcn_mfma_f32_16x16x32_bf16(pA1, vB1[nt], Oacc[nt], 0, 0, 0);
    }
  }

  float inv[4];
#pragma unroll
  for (int r = 0; r < 4; ++r) {
    float ps = psum[r];
    ps += __shfl_xor(ps, 1);
    ps += __shfl_xor(ps, 2);
    ps += __shfl_xor(ps, 4);
    ps += __shfl_xor(ps, 8);
    inv[r] = 1.0f / ps;
  }
#pragma unroll
  for (int nt = 0; nt < 4; ++nt) {
#pragma unroll
    for (int r = 0; r < 4; ++r) {
      const int q = qb + quad * 4 + r;
      Aout[((size_t)b * 1024 + q) * 1024 + h * 64 + nt * 16 + l16] =
          (__bf16)(Oacc[nt][r] * inv[r]);
    }
  }
}

// ---------------- launch ----------------
extern "C" void kernel_launch(void* const* d_in, const int* in_sizes, int n_in,
                              void* d_out, int out_size, void* d_ws,
                              size_t ws_size, hipStream_t stream) {
  const float* x      = (const float*)d_in[0];
  const float* w_attn = (const float*)d_in[1];
  const float* b_attn = (const float*)d_in[2];
  const float* w_proj = (const float*)d_in[3];
  const float* b_proj = (const float*)d_in[4];
  float* out = (float*)d_out;

  char* ws = (char*)d_ws;
  __bf16* WT_attn = (__bf16*)(ws);                  //  6 MB
  __bf16* WT_proj = (__bf16*)(ws + 6291456);        //  2 MB
  __bf16* Xb      = (__bf16*)(ws + 8388608);        //  8 MB (reused as VT)
  __bf16* QKV     = (__bf16*)(ws + 16777216);       // 24 MB
  __bf16* Aattn   = (__bf16*)(ws + 41943040);       //  8 MB  (end 48 MB)
  __bf16* Opart   = (__bf16*)(ws + 50331648);       // 20 MB: 10240 x 1024 bf16
  float*  Lpart   = (float*)(ws + 71303168);        // 640 KB (end ~68.6 MB)
  __bf16* VT      = Xb;

  transpose_f32_bf16<<<dim3(96, 32), dim3(32, 8), 0, stream>>>(
      w_attn, WT_attn, 1024, 3072);
  transpose_f32_bf16<<<dim3(32, 32), dim3(32, 8), 0, stream>>>(
      w_proj, WT_proj, 1024, 1024);
  f32_to_bf16<<<4096, 256, 0, stream>>>(x, Xb, 4096 * 1024);
  gemm_bt_bias<__bf16><<<dim3(24, 32), 256, 0, stream>>>(
      Xb, WT_attn, b_attn, QKV, 4096, 3072, 1024);
  transpose_v<<<1024, 256, 0, stream>>>(QKV, VT);

  if (ws_size >= 72000000ull) {
    attn_split<<<10240, 64, 0, stream>>>(QKV, VT, Opart, Lpart);
    attn_reduce<<<4096, 256, 0, stream>>>(Opart, Lpart, Aattn);
  } else {
    attn_mfma<<<4096, 64, 0, stream>>>(QKV, VT, Aattn);
  }

  gemm_bt_bias<float><<<dim3(8, 32), 256, 0, stream>>>(
      Aattn, WT_proj, b_proj, out, 4096, 1024, 1024);
}

// Round 8
// 187.491 us; speedup vs baseline: 1.2907x; 1.2907x over previous
//
#include <hip/hip_runtime.h>
#include <hip/hip_bf16.h>

// GPT-2 attention block. Inputs/outputs fp32; internal bf16 MFMA, fp32 accum.
// B=4, S=1024, D=1024, H=16, hd=64.
//
// R8 = R7 with the pack_kv K-indexing bug fixed (was writing 128 keys x half
//      the d-range, leaving Kp[.., 32..63] poisoned).
//     attention: 4 waves share DMA-staged K/V in LDS; causal pairing (q-tiles
//     pr and 15-pr -> uniform 9 tile-computations/block); packed K lines;
//     direct-exp softmax; 2 barriers/iter.

typedef __bf16 bf16x8 __attribute__((ext_vector_type(8)));
typedef float f32x4 __attribute__((ext_vector_type(4)));

__device__ __forceinline__ void load_lds16(const void* g, void* l) {
  __builtin_amdgcn_global_load_lds(
      (const __attribute__((address_space(1))) void*)g,
      (__attribute__((address_space(3))) void*)l, 16, 0, 0);
}

// ---------------- convert fp32 -> bf16 ----------------
__global__ __launch_bounds__(256) void f32_to_bf16(
    const float* __restrict__ in, __bf16* __restrict__ out, int n) {
  int i = (blockIdx.x * 256 + threadIdx.x) * 4;
  if (i + 3 < n) {
    float4 v = *(const float4*)(in + i);
    out[i + 0] = (__bf16)v.x;
    out[i + 1] = (__bf16)v.y;
    out[i + 2] = (__bf16)v.z;
    out[i + 3] = (__bf16)v.w;
  }
}

// ---------------- convert+transpose: WT[n*K+k] = (bf16)W[k*N+n] ----------------
__global__ __launch_bounds__(256) void transpose_f32_bf16(
    const float* __restrict__ W, __bf16* __restrict__ WT, int K, int N) {
  __shared__ __bf16 tile[32][33];
  int n0 = blockIdx.x * 32, k0 = blockIdx.y * 32;
  int tx = threadIdx.x, ty = threadIdx.y;  // block (32,8)
#pragma unroll
  for (int j = 0; j < 32; j += 8)
    tile[ty + j][tx] = (__bf16)W[(size_t)(k0 + ty + j) * N + n0 + tx];
  __syncthreads();
#pragma unroll
  for (int j = 0; j < 32; j += 8)
    WT[(size_t)(n0 + ty + j) * K + k0 + tx] = tile[tx][ty + j];
}

// ---------------- pack K + transpose V (one dispatch) ----------------
// Kp[bh][key][64]: key row = one full 128B line. VT[bh][d][1024].
__global__ __launch_bounds__(256) void pack_kv(
    const __bf16* __restrict__ qkv, __bf16* __restrict__ Kp,
    __bf16* __restrict__ VT) {
  const int tid = threadIdx.x;
  const int lane = tid & 63, wave = tid >> 6;
  const int bh = blockIdx.x >> 4;
  const int kb = (blockIdx.x & 15) * 64;
  const int b = bh >> 4, h = bh & 15;

  // V transpose (verified R4 pattern)
  const __bf16* srcv =
      qkv + ((size_t)b * 1024 + kb + lane) * 3072 + 2048 + h * 64 + wave * 16;
  bf16x8 v0 = *(const bf16x8*)srcv;
  bf16x8 v1 = *(const bf16x8*)(srcv + 8);
  __bf16* dstv = VT + ((size_t)bh * 64 + wave * 16) * 1024 + kb + lane;
#pragma unroll
  for (int i = 0; i < 8; ++i) {
    dstv[(size_t)i * 1024] = v0[i];
    dstv[(size_t)(i + 8) * 1024] = v1[i];
  }

  // K pack: 64 keys x 64 d, 8 chunks of 8 bf16 per key (FIXED: was >>2 / &3)
#pragma unroll
  for (int p = 0; p < 2; ++p) {
    const int idx = p * 256 + tid;        // 0..511
    const int key = kb + (idx >> 3);      // 64 keys
    const int c = (idx & 7) * 8;          // 8 chunks: full d range
    *(bf16x8*)(Kp + (size_t)bh * 65536 + (size_t)key * 64 + c) =
        *(const bf16x8*)(qkv + ((size_t)b * 1024 + key) * 3072 + 1024 + h * 64 + c);
  }
}

// ---------------- GEMM (m97 structure): C = A @ BT^T + bias ----------------
template <typename OutT>
__global__ __launch_bounds__(256) void gemm_bt_bias(
    const __bf16* __restrict__ A, const __bf16* __restrict__ BT,
    const float* __restrict__ bias, OutT* __restrict__ C, int M, int N, int K) {
  __shared__ __bf16 sA[128 * 32];
  __shared__ __bf16 sB[128 * 32];

  const int tid = threadIdx.x;
  const int lane = tid & 63;
  const int wave = tid >> 6;
  const int waveM = wave >> 1, waveN = wave & 1;
  const int quad = lane >> 4;
  const int l16 = lane & 15;
  const int rowBase = blockIdx.y * 128;
  const int colBase = blockIdx.x * 128;

  const int rIn = lane >> 2;
  const int sIn = lane & 3;
  const int gc = sIn ^ (rIn & 3) ^ ((rIn >> 2) & 3);
  const int readSlot = quad ^ (l16 & 3) ^ ((l16 >> 2) & 3);

  f32x4 acc[4][4] = {};

  for (int k0 = 0; k0 < K; k0 += 32) {
    __syncthreads();
#pragma unroll
    for (int j = 0; j < 2; ++j) {
      const int rb = wave * 32 + j * 16;
      load_lds16(&A[(size_t)(rowBase + rb + rIn) * K + k0 + gc * 8], &sA[rb * 32]);
      load_lds16(&BT[(size_t)(colBase + rb + rIn) * K + k0 + gc * 8], &sB[rb * 32]);
    }
    __syncthreads();

    bf16x8 af[4], bfr[4];
#pragma unroll
    for (int mt = 0; mt < 4; ++mt)
      af[mt] = *(const bf16x8*)(&sA[(waveM * 64 + mt * 16 + l16) * 32 + readSlot * 8]);
#pragma unroll
    for (int nt = 0; nt < 4; ++nt)
      bfr[nt] = *(const bf16x8*)(&sB[(waveN * 64 + nt * 16 + l16) * 32 + readSlot * 8]);
#pragma unroll
    for (int mt = 0; mt < 4; ++mt)
#pragma unroll
      for (int nt = 0; nt < 4; ++nt)
        acc[mt][nt] = __builtin_amdgcn_mfma_f32_16x16x32_bf16(
            af[mt], bfr[nt], acc[mt][nt], 0, 0, 0);
  }

#pragma unroll
  for (int mt = 0; mt < 4; ++mt) {
    int row = rowBase + waveM * 64 + mt * 16 + quad * 4;
#pragma unroll
    for (int nt = 0; nt < 4; ++nt) {
      int col = colBase + waveN * 64 + nt * 16 + l16;
      float bv = bias[col];
#pragma unroll
      for (int r = 0; r < 4; ++r)
        C[(size_t)(row + r) * N + col] = (OutT)(acc[mt][nt][r] + bv);
    }
  }
}

// ---------------- paired flash attention ----------------
// Block = (bh, pair pr). q-tiles qtA=pr, qtB=15-pr (64 rows each): uniform 9
// tile-computations. Per 128-key tile: DMA-stage sK (packed lines) + sV,
// QK^T -> direct exp -> P via wave-private LDS -> PV.
__global__ __launch_bounds__(256) void attn_mfma(
    const __bf16* __restrict__ qkv, const __bf16* __restrict__ Kp,
    const __bf16* __restrict__ VT, __bf16* __restrict__ Aout) {
  __shared__ __bf16 sK[128 * 64];      // 16 KB, swizzled packed K lines
  __shared__ __bf16 sV[64 * 128];      // 16 KB, swizzled V^T
  __shared__ __bf16 sP[4 * 16 * 128];  // 16 KB, per-wave P regions

  const int tid = threadIdx.x;
  const int lane = tid & 63;
  const int wave = tid >> 6;
  const int quad = lane >> 4;
  const int l16 = lane & 15;
  const int swq = l16 & 7;

  const int bh = blockIdx.x >> 3;
  const int pr = blockIdx.x & 7;
  const int b = bh >> 4, h = bh & 15;
  const int qbA = pr * 64, qbB = (15 - pr) * 64;
  const int ktA_max = pr >> 1, ktB_max = (15 - pr) >> 1;

  const size_t rowS = 3072;
  const __bf16* Qb = qkv + (size_t)b * 1024 * rowS + h * 64;
  const __bf16* Kb = Kp + (size_t)bh * 65536;
  const __bf16* VTb = VT + (size_t)bh * 64 * 1024;

  bf16x8 qA0A, qA1A, qA0B, qA1B;
  {
    const __bf16* qr = Qb + (size_t)(qbA + wave * 16 + l16) * rowS + quad * 8;
    qA0A = *(const bf16x8*)qr;
    qA1A = *(const bf16x8*)(qr + 32);
    qr = Qb + (size_t)(qbB + wave * 16 + l16) * rowS + quad * 8;
    qA0B = *(const bf16x8*)qr;
    qA1B = *(const bf16x8*)(qr + 32);
  }

  f32x4 OA[4] = {}, OB[4] = {};
  float psA[4] = {0.f, 0.f, 0.f, 0.f}, psB[4] = {0.f, 0.f, 0.f, 0.f};
  __bf16* pw = sP + wave * 2048;

  for (int kt = 0; kt <= ktB_max; ++kt) {
    const int kb = kt * 128;
    __syncthreads();  // prior iter's sK/sV reads complete

    // ---- DMA stage K: sK[key][slot s] = line chunk s^(key&7)
#pragma unroll
    for (int i = 0; i < 4; ++i) {
      const int rb = wave * 32 + i * 8;  // key base, multiple of 8
      load_lds16(Kb + (size_t)(kb + rb + (lane >> 3)) * 64 +
                     (((lane & 7) ^ ((lane >> 3) & 7)) << 3),
                 &sK[rb * 64]);
    }
    // ---- DMA stage V^T: sV[d][slot s] = key-chunk s^(d&7)
#pragma unroll
    for (int i = 0; i < 4; ++i) {
      const int db = wave * 16 + i * 4;
      const int d = db + (lane >> 4);
      load_lds16(VTb + (size_t)d * 1024 + kb + (((lane & 15) ^ (d & 7)) << 3),
                 &sV[db * 128]);
    }
    __syncthreads();  // staged (barrier drains vmcnt)

    // ================= q-tile B (always active) =================
    {
      float sc[8][4];
#pragma unroll
      for (int n = 0; n < 8; ++n) {
        const int key = n * 16 + l16;
        bf16x8 kB0 = *(const bf16x8*)(&sK[key * 64 + ((quad ^ swq) << 3)]);
        bf16x8 kB1 = *(const bf16x8*)(&sK[key * 64 + (((quad + 4) ^ swq) << 3)]);
        f32x4 c = {};
        c = __builtin_amdgcn_mfma_f32_16x16x32_bf16(qA0B, kB0, c, 0, 0, 0);
        c = __builtin_amdgcn_mfma_f32_16x16x32_bf16(qA1B, kB1, c, 0, 0, 0);
#pragma unroll
        for (int r = 0; r < 4; ++r) sc[n][r] = c[r] * 0.125f;
      }
      if (kt == ktB_max) {
#pragma unroll
        for (int n = 0; n < 8; ++n) {
          const int kg = kb + n * 16 + l16;
#pragma unroll
          for (int r = 0; r < 4; ++r)
            if (kg > qbB + wave * 16 + quad * 4 + r) sc[n][r] = -1.0e30f;
        }
      }
#pragma unroll
      for (int n = 0; n < 8; ++n)
#pragma unroll
        for (int r = 0; r < 4; ++r) {
          float p = __expf(fminf(sc[n][r], 60.0f));
          sc[n][r] = p;
          psB[r] += p;
        }
      // P scatter (wave-private; DS ops in-order per wave)
      {
        const int kb8 = l16 >> 3, lo = l16 & 7;
#pragma unroll
        for (int n = 0; n < 8; ++n) {
          const int chunk = n * 2 + kb8;
#pragma unroll
          for (int r = 0; r < 4; ++r) {
            const int q = quad * 4 + r;
            pw[q * 128 + ((chunk ^ (q & 7)) << 3) + lo] = (__bf16)sc[n][r];
          }
        }
      }
#pragma unroll
      for (int cc = 0; cc < 4; ++cc) {
        bf16x8 pA = *(const bf16x8*)(&pw[l16 * 128 + (((cc * 4 + quad) ^ swq) << 3)]);
#pragma unroll
        for (int nt = 0; nt < 4; ++nt) {
          bf16x8 vB = *(const bf16x8*)(&sV[(nt * 16 + l16) * 128 +
                                           (((cc * 4 + quad) ^ swq) << 3)]);
          OB[nt] = __builtin_amdgcn_mfma_f32_16x16x32_bf16(pA, vB, OB[nt], 0, 0, 0);
        }
      }
    }

    // ================= q-tile A (active while kt <= ktA_max) =================
    if (kt <= ktA_max) {
      float sc[8][4];
#pragma unroll
      for (int n = 0; n < 8; ++n) {
        const int key = n * 16 + l16;
        bf16x8 kB0 = *(const bf16x8*)(&sK[key * 64 + ((quad ^ swq) << 3)]);
        bf16x8 kB1 = *(const bf16x8*)(&sK[key * 64 + (((quad + 4) ^ swq) << 3)]);
        f32x4 c = {};
        c = __builtin_amdgcn_mfma_f32_16x16x32_bf16(qA0A, kB0, c, 0, 0, 0);
        c = __builtin_amdgcn_mfma_f32_16x16x32_bf16(qA1A, kB1, c, 0, 0, 0);
#pragma unroll
        for (int r = 0; r < 4; ++r) sc[n][r] = c[r] * 0.125f;
      }
      if (kt == ktA_max) {
#pragma unroll
        for (int n = 0; n < 8; ++n) {
          const int kg = kb + n * 16 + l16;
#pragma unroll
          for (int r = 0; r < 4; ++r)
            if (kg > qbA + wave * 16 + quad * 4 + r) sc[n][r] = -1.0e30f;
        }
      }
#pragma unroll
      for (int n = 0; n < 8; ++n)
#pragma unroll
        for (int r = 0; r < 4; ++r) {
          float p = __expf(fminf(sc[n][r], 60.0f));
          sc[n][r] = p;
          psA[r] += p;
        }
      {
        const int kb8 = l16 >> 3, lo = l16 & 7;
#pragma unroll
        for (int n = 0; n < 8; ++n) {
          const int chunk = n * 2 + kb8;
#pragma unroll
          for (int r = 0; r < 4; ++r) {
            const int q = quad * 4 + r;
            pw[q * 128 + ((chunk ^ (q & 7)) << 3) + lo] = (__bf16)sc[n][r];
          }
        }
      }
#pragma unroll
      for (int cc = 0; cc < 4; ++cc) {
        bf16x8 pA = *(const bf16x8*)(&pw[l16 * 128 + (((cc * 4 + quad) ^ swq) << 3)]);
#pragma unroll
        for (int nt = 0; nt < 4; ++nt) {
          bf16x8 vB = *(const bf16x8*)(&sV[(nt * 16 + l16) * 128 +
                                           (((cc * 4 + quad) ^ swq) << 3)]);
          OA[nt] = __builtin_amdgcn_mfma_f32_16x16x32_bf16(pA, vB, OA[nt], 0, 0, 0);
        }
      }
    }
  }

  // ---- epilogue: one reduction per q-tile, normalize, store
  float invA[4], invB[4];
#pragma unroll
  for (int r = 0; r < 4; ++r) {
    float pa = psA[r], pb = psB[r];
    pa += __shfl_xor(pa, 1); pb += __shfl_xor(pb, 1);
    pa += __shfl_xor(pa, 2); pb += __shfl_xor(pb, 2);
    pa += __shfl_xor(pa, 4); pb += __shfl_xor(pb, 4);
    pa += __shfl_xor(pa, 8); pb += __shfl_xor(pb, 8);
    invA[r] = 1.0f / pa;
    invB[r] = 1.0f / pb;
  }
#pragma unroll
  for (int nt = 0; nt < 4; ++nt) {
#pragma unroll
    for (int r = 0; r < 4; ++r) {
      const int qA = qbA + wave * 16 + quad * 4 + r;
      const int qB = qbB + wave * 16 + quad * 4 + r;
      Aout[((size_t)b * 1024 + qA) * 1024 + h * 64 + nt * 16 + l16] =
          (__bf16)(OA[nt][r] * invA[r]);
      Aout[((size_t)b * 1024 + qB) * 1024 + h * 64 + nt * 16 + l16] =
          (__bf16)(OB[nt][r] * invB[r]);
    }
  }
}

// ---------------- launch ----------------
extern "C" void kernel_launch(void* const* d_in, const int* in_sizes, int n_in,
                              void* d_out, int out_size, void* d_ws,
                              size_t ws_size, hipStream_t stream) {
  const float* x      = (const float*)d_in[0];
  const float* w_attn = (const float*)d_in[1];
  const float* b_attn = (const float*)d_in[2];
  const float* w_proj = (const float*)d_in[3];
  const float* b_proj = (const float*)d_in[4];
  float* out = (float*)d_out;

  char* ws = (char*)d_ws;
  __bf16* WT_attn = (__bf16*)(ws);                  //  6 MB
  __bf16* WT_proj = (__bf16*)(ws + 6291456);        //  2 MB
  __bf16* Xb      = (__bf16*)(ws + 8388608);        //  8 MB (reused as VT)
  __bf16* QKV     = (__bf16*)(ws + 16777216);       // 24 MB
  __bf16* Aattn   = (__bf16*)(ws + 41943040);       //  8 MB (end 48 MB)
  __bf16* Kp      = (__bf16*)(ws + 50331648);       //  8 MB packed K
  __bf16* VT      = Xb;  // x-as-bf16 dead after GEMM1

  transpose_f32_bf16<<<dim3(96, 32), dim3(32, 8), 0, stream>>>(
      w_attn, WT_attn, 1024, 3072);
  transpose_f32_bf16<<<dim3(32, 32), dim3(32, 8), 0, stream>>>(
      w_proj, WT_proj, 1024, 1024);
  f32_to_bf16<<<4096, 256, 0, stream>>>(x, Xb, 4096 * 1024);
  gemm_bt_bias<__bf16><<<dim3(24, 32), 256, 0, stream>>>(
      Xb, WT_attn, b_attn, QKV, 4096, 3072, 1024);
  pack_kv<<<1024, 256, 0, stream>>>(QKV, Kp, VT);
  attn_mfma<<<512, 256, 0, stream>>>(QKV, Kp, VT, Aattn);
  gemm_bt_bias<float><<<dim3(8, 32), 256, 0, stream>>>(
      Aattn, WT_proj, b_proj, out, 4096, 1024, 1024);
}

// Round 9
// 186.058 us; speedup vs baseline: 1.3007x; 1.0077x over previous
//
#include <hip/hip_runtime.h>
#include <hip/hip_bf16.h>

// GPT-2 attention block. Inputs/outputs fp32; internal bf16 MFMA, fp32 accum.
// B=4, S=1024, D=1024, H=16, hd=64.
//
// R9: GEMMs: BK=64 (half the barriers), natural m97 chunk mapping with
//     XOR-by-row swizzle for the 128B-row LDS (attn-sK pattern). GEMM1
//     epilogue writes packed Qp/Kp[bh][s][64] + Vr[s][1024] directly.
//     Prep (2 weight transposes + x convert) fused into one dispatch.
//     Attention unchanged from R8 (paired causal, DMA-staged, direct-exp).

typedef __bf16 bf16x8 __attribute__((ext_vector_type(8)));
typedef float f32x4 __attribute__((ext_vector_type(4)));

__device__ __forceinline__ void load_lds16(const void* g, void* l) {
  __builtin_amdgcn_global_load_lds(
      (const __attribute__((address_space(1))) void*)g,
      (__attribute__((address_space(3))) void*)l, 16, 0, 0);
}

// ---------------- fused prep: transpose w_attn, w_proj; convert x ----------------
__global__ __launch_bounds__(256) void prep(
    const float* __restrict__ x, const float* __restrict__ w_attn,
    const float* __restrict__ w_proj, __bf16* __restrict__ Xb,
    __bf16* __restrict__ WT_attn, __bf16* __restrict__ WT_proj) {
  __shared__ __bf16 tile[32][33];
  const int blk = blockIdx.x;
  const int tid = threadIdx.x;
  if (blk < 4096) {  // transpose (block-uniform branch)
    const float* W;
    __bf16* WT;
    int n0, k0, N;
    if (blk < 3072) {
      W = w_attn; WT = WT_attn; N = 3072;
      n0 = (blk % 96) * 32; k0 = (blk / 96) * 32;
    } else {
      W = w_proj; WT = WT_proj; N = 1024;
      const int t = blk - 3072;
      n0 = (t & 31) * 32; k0 = (t >> 5) * 32;
    }
    const int tx = tid & 31, ty = tid >> 5;
#pragma unroll
    for (int j = 0; j < 32; j += 8)
      tile[ty + j][tx] = (__bf16)W[(size_t)(k0 + ty + j) * N + n0 + tx];
    __syncthreads();
#pragma unroll
    for (int j = 0; j < 32; j += 8)
      WT[(size_t)(n0 + ty + j) * 1024 + k0 + tx] = tile[tx][ty + j];
  } else {  // x -> bf16, 16 elems/thread
    const size_t i = (size_t)(blk - 4096) * 4096 + tid * 16;
    const float4* xp = (const float4*)(x + i);
    float4 a = xp[0], b = xp[1], c = xp[2], d = xp[3];
    bf16x8 o0, o1;
    o0[0] = (__bf16)a.x; o0[1] = (__bf16)a.y; o0[2] = (__bf16)a.z; o0[3] = (__bf16)a.w;
    o0[4] = (__bf16)b.x; o0[5] = (__bf16)b.y; o0[6] = (__bf16)b.z; o0[7] = (__bf16)b.w;
    o1[0] = (__bf16)c.x; o1[1] = (__bf16)c.y; o1[2] = (__bf16)c.z; o1[3] = (__bf16)c.w;
    o1[4] = (__bf16)d.x; o1[5] = (__bf16)d.y; o1[6] = (__bf16)d.z; o1[7] = (__bf16)d.w;
    *(bf16x8*)(Xb + i) = o0;
    *(bf16x8*)(Xb + i + 8) = o1;
  }
}

// ---------------- V transpose: VT[bh][d][s] from Vr[s_global][1024] ----------------
__global__ __launch_bounds__(256) void transpose_v(
    const __bf16* __restrict__ Vr, __bf16* __restrict__ VT) {
  const int lane = threadIdx.x & 63, wave = threadIdx.x >> 6;
  const int bh = blockIdx.x >> 4;
  const int kb = (blockIdx.x & 15) * 64;
  const int b = bh >> 4, h = bh & 15;
  const __bf16* src =
      Vr + (size_t)(b * 1024 + kb + lane) * 1024 + h * 64 + wave * 16;
  bf16x8 v0 = *(const bf16x8*)src;
  bf16x8 v1 = *(const bf16x8*)(src + 8);
  __bf16* dst = VT + ((size_t)bh * 64 + wave * 16) * 1024 + kb + lane;
#pragma unroll
  for (int i = 0; i < 8; ++i) {
    dst[(size_t)i * 1024] = v0[i];
    dst[(size_t)(i + 8) * 1024] = v1[i];
  }
}

// ================= GEMM core macro-free shared structure =================
// 128x128 tile, BK=64, LDS [128][64] (128B rows), chunk c of row r at slot
// c^(r&7) (attn-sK pattern; staged via global_load_lds with swizzled source).
#define GEMM_CORE(A_, BT_, K_)                                                   \
  __shared__ __bf16 sA[128 * 64];                                                \
  __shared__ __bf16 sB[128 * 64];                                                \
  const int tid = threadIdx.x;                                                   \
  const int lane = tid & 63;                                                     \
  const int wave = tid >> 6;                                                     \
  const int waveM = wave >> 1, waveN = wave & 1;                                 \
  const int quad = lane >> 4;                                                    \
  const int l16 = lane & 15;                                                     \
  const int rowBase = blockIdx.y * 128;                                          \
  const int colBase = blockIdx.x * 128;                                          \
  const int sr = lane >> 3;                                                      \
  const int ss = lane & 7;                                                       \
  const int gcs = ss ^ sr;                                                       \
  const int swl = l16 & 7;                                                       \
  f32x4 acc[4][4] = {};                                                          \
  for (int k0 = 0; k0 < K_; k0 += 64) {                                          \
    __syncthreads();                                                             \
    _Pragma("unroll") for (int i = 0; i < 4; ++i) {                              \
      const int rb = wave * 32 + i * 8;                                          \
      load_lds16(&A_[(size_t)(rowBase + rb + sr) * K_ + k0 + gcs * 8],           \
                 &sA[rb * 64]);                                                  \
      load_lds16(&BT_[(size_t)(colBase + rb + sr) * K_ + k0 + gcs * 8],          \
                 &sB[rb * 64]);                                                  \
    }                                                                            \
    __syncthreads();                                                             \
    bf16x8 af0[4], af1[4], bf0[4], bf1[4];                                       \
    _Pragma("unroll") for (int mt = 0; mt < 4; ++mt) {                           \
      const int row = waveM * 64 + mt * 16 + l16;                                \
      af0[mt] = *(const bf16x8*)(&sA[row * 64 + ((quad ^ swl) << 3)]);           \
      af1[mt] = *(const bf16x8*)(&sA[row * 64 + (((quad + 4) ^ swl) << 3)]);     \
    }                                                                            \
    _Pragma("unroll") for (int nt = 0; nt < 4; ++nt) {                           \
      const int row = waveN * 64 + nt * 16 + l16;                                \
      bf0[nt] = *(const bf16x8*)(&sB[row * 64 + ((quad ^ swl) << 3)]);           \
      bf1[nt] = *(const bf16x8*)(&sB[row * 64 + (((quad + 4) ^ swl) << 3)]);     \
    }                                                                            \
    _Pragma("unroll") for (int mt = 0; mt < 4; ++mt)                             \
    _Pragma("unroll") for (int nt = 0; nt < 4; ++nt) {                           \
      acc[mt][nt] = __builtin_amdgcn_mfma_f32_16x16x32_bf16(                     \
          af0[mt], bf0[nt], acc[mt][nt], 0, 0, 0);                               \
      acc[mt][nt] = __builtin_amdgcn_mfma_f32_16x16x32_bf16(                     \
          af1[mt], bf1[nt], acc[mt][nt], 0, 0, 0);                               \
    }                                                                            \
  }

// ---------------- GEMM1: QKV, epilogue writes packed Qp/Kp/Vr ----------------
__global__ __launch_bounds__(256) void gemm_qkv(
    const __bf16* __restrict__ A, const __bf16* __restrict__ BT,
    const float* __restrict__ bias, __bf16* __restrict__ Qp,
    __bf16* __restrict__ Kp, __bf16* __restrict__ Vr) {
  GEMM_CORE(A, BT, 1024)
  const int seg = colBase >> 10;  // 0=Q 1=K 2=V (block-uniform)
#pragma unroll
  for (int mt = 0; mt < 4; ++mt) {
    const int row0 = rowBase + waveM * 64 + mt * 16 + quad * 4;
#pragma unroll
    for (int nt = 0; nt < 4; ++nt) {
      const int col = colBase + waveN * 64 + nt * 16 + l16;
      const float bv = bias[col];
      const int cc = col & 1023;
#pragma unroll
      for (int r = 0; r < 4; ++r) {
        const int row = row0 + r;
        const float v = acc[mt][nt][r] + bv;
        if (seg == 2) {
          Vr[(size_t)row * 1024 + cc] = (__bf16)v;
        } else {
          const int bh = ((row >> 10) << 4) + (cc >> 6);
          __bf16* dst = (seg == 0) ? Qp : Kp;
          dst[((size_t)bh << 16) + (size_t)(row & 1023) * 64 + (cc & 63)] =
              (__bf16)v;
        }
      }
    }
  }
}

// ---------------- GEMM2: out = A @ WT^T + bias (fp32 out) ----------------
__global__ __launch_bounds__(256) void gemm_out(
    const __bf16* __restrict__ A, const __bf16* __restrict__ BT,
    const float* __restrict__ bias, float* __restrict__ C) {
  GEMM_CORE(A, BT, 1024)
#pragma unroll
  for (int mt = 0; mt < 4; ++mt) {
    const int row = rowBase + waveM * 64 + mt * 16 + quad * 4;
#pragma unroll
    for (int nt = 0; nt < 4; ++nt) {
      const int col = colBase + waveN * 64 + nt * 16 + l16;
      const float bv = bias[col];
#pragma unroll
      for (int r = 0; r < 4; ++r)
        C[(size_t)(row + r) * 1024 + col] = acc[mt][nt][r] + bv;
    }
  }
}

// ---------------- paired flash attention (R8, Q from packed Qp) ----------------
__global__ __launch_bounds__(256) void attn_mfma(
    const __bf16* __restrict__ Qp, const __bf16* __restrict__ Kp,
    const __bf16* __restrict__ VT, __bf16* __restrict__ Aout) {
  __shared__ __bf16 sK[128 * 64];      // 16 KB, swizzled packed K lines
  __shared__ __bf16 sV[64 * 128];      // 16 KB, swizzled V^T
  __shared__ __bf16 sP[4 * 16 * 128];  // 16 KB, per-wave P regions

  const int tid = threadIdx.x;
  const int lane = tid & 63;
  const int wave = tid >> 6;
  const int quad = lane >> 4;
  const int l16 = lane & 15;
  const int swq = l16 & 7;

  const int bh = blockIdx.x >> 3;
  const int pr = blockIdx.x & 7;
  const int b = bh >> 4, h = bh & 15;
  const int qbA = pr * 64, qbB = (15 - pr) * 64;
  const int ktA_max = pr >> 1, ktB_max = (15 - pr) >> 1;

  const __bf16* Qb = Qp + ((size_t)bh << 16);
  const __bf16* Kb = Kp + ((size_t)bh << 16);
  const __bf16* VTb = VT + (size_t)bh * 64 * 1024;

  bf16x8 qA0A, qA1A, qA0B, qA1B;
  {
    const __bf16* qr = Qb + (size_t)(qbA + wave * 16 + l16) * 64 + quad * 8;
    qA0A = *(const bf16x8*)qr;
    qA1A = *(const bf16x8*)(qr + 32);
    qr = Qb + (size_t)(qbB + wave * 16 + l16) * 64 + quad * 8;
    qA0B = *(const bf16x8*)qr;
    qA1B = *(const bf16x8*)(qr + 32);
  }

  f32x4 OA[4] = {}, OB[4] = {};
  float psA[4] = {0.f, 0.f, 0.f, 0.f}, psB[4] = {0.f, 0.f, 0.f, 0.f};
  __bf16* pw = sP + wave * 2048;

  for (int kt = 0; kt <= ktB_max; ++kt) {
    const int kb = kt * 128;
    __syncthreads();  // prior iter's sK/sV reads complete

    // ---- DMA stage K: sK[key][slot s] = line chunk s^(key&7)
#pragma unroll
    for (int i = 0; i < 4; ++i) {
      const int rb = wave * 32 + i * 8;
      load_lds16(Kb + (size_t)(kb + rb + (lane >> 3)) * 64 +
                     (((lane & 7) ^ ((lane >> 3) & 7)) << 3),
                 &sK[rb * 64]);
    }
    // ---- DMA stage V^T: sV[d][slot s] = key-chunk s^(d&7)
#pragma unroll
    for (int i = 0; i < 4; ++i) {
      const int db = wave * 16 + i * 4;
      const int d = db + (lane >> 4);
      load_lds16(VTb + (size_t)d * 1024 + kb + (((lane & 15) ^ (d & 7)) << 3),
                 &sV[db * 128]);
    }
    __syncthreads();  // staged

    // ================= q-tile B (always active) =================
    {
      float sc[8][4];
#pragma unroll
      for (int n = 0; n < 8; ++n) {
        const int key = n * 16 + l16;
        bf16x8 kB0 = *(const bf16x8*)(&sK[key * 64 + ((quad ^ swq) << 3)]);
        bf16x8 kB1 = *(const bf16x8*)(&sK[key * 64 + (((quad + 4) ^ swq) << 3)]);
        f32x4 c = {};
        c = __builtin_amdgcn_mfma_f32_16x16x32_bf16(qA0B, kB0, c, 0, 0, 0);
        c = __builtin_amdgcn_mfma_f32_16x16x32_bf16(qA1B, kB1, c, 0, 0, 0);
#pragma unroll
        for (int r = 0; r < 4; ++r) sc[n][r] = c[r] * 0.125f;
      }
      if (kt == ktB_max) {
#pragma unroll
        for (int n = 0; n < 8; ++n) {
          const int kg = kb + n * 16 + l16;
#pragma unroll
          for (int r = 0; r < 4; ++r)
            if (kg > qbB + wave * 16 + quad * 4 + r) sc[n][r] = -1.0e30f;
        }
      }
#pragma unroll
      for (int n = 0; n < 8; ++n)
#pragma unroll
        for (int r = 0; r < 4; ++r) {
          float p = __expf(fminf(sc[n][r], 60.0f));
          sc[n][r] = p;
          psB[r] += p;
        }
      {
        const int kb8 = l16 >> 3, lo = l16 & 7;
#pragma unroll
        for (int n = 0; n < 8; ++n) {
          const int chunk = n * 2 + kb8;
#pragma unroll
          for (int r = 0; r < 4; ++r) {
            const int q = quad * 4 + r;
            pw[q * 128 + ((chunk ^ (q & 7)) << 3) + lo] = (__bf16)sc[n][r];
          }
        }
      }
#pragma unroll
      for (int cc = 0; cc < 4; ++cc) {
        bf16x8 pA = *(const bf16x8*)(&pw[l16 * 128 + (((cc * 4 + quad) ^ swq) << 3)]);
#pragma unroll
        for (int nt = 0; nt < 4; ++nt) {
          bf16x8 vB = *(const bf16x8*)(&sV[(nt * 16 + l16) * 128 +
                                           (((cc * 4 + quad) ^ swq) << 3)]);
          OB[nt] = __builtin_amdgcn_mfma_f32_16x16x32_bf16(pA, vB, OB[nt], 0, 0, 0);
        }
      }
    }

    // ================= q-tile A (active while kt <= ktA_max) =================
    if (kt <= ktA_max) {
      float sc[8][4];
#pragma unroll
      for (int n = 0; n < 8; ++n) {
        const int key = n * 16 + l16;
        bf16x8 kB0 = *(const bf16x8*)(&sK[key * 64 + ((quad ^ swq) << 3)]);
        bf16x8 kB1 = *(const bf16x8*)(&sK[key * 64 + (((quad + 4) ^ swq) << 3)]);
        f32x4 c = {};
        c = __builtin_amdgcn_mfma_f32_16x16x32_bf16(qA0A, kB0, c, 0, 0, 0);
        c = __builtin_amdgcn_mfma_f32_16x16x32_bf16(qA1A, kB1, c, 0, 0, 0);
#pragma unroll
        for (int r = 0; r < 4; ++r) sc[n][r] = c[r] * 0.125f;
      }
      if (kt == ktA_max) {
#pragma unroll
        for (int n = 0; n < 8; ++n) {
          const int kg = kb + n * 16 + l16;
#pragma unroll
          for (int r = 0; r < 4; ++r)
            if (kg > qbA + wave * 16 + quad * 4 + r) sc[n][r] = -1.0e30f;
        }
      }
#pragma unroll
      for (int n = 0; n < 8; ++n)
#pragma unroll
        for (int r = 0; r < 4; ++r) {
          float p = __expf(fminf(sc[n][r], 60.0f));
          sc[n][r] = p;
          psA[r] += p;
        }
      {
        const int kb8 = l16 >> 3, lo = l16 & 7;
#pragma unroll
        for (int n = 0; n < 8; ++n) {
          const int chunk = n * 2 + kb8;
#pragma unroll
          for (int r = 0; r < 4; ++r) {
            const int q = quad * 4 + r;
            pw[q * 128 + ((chunk ^ (q & 7)) << 3) + lo] = (__bf16)sc[n][r];
          }
        }
      }
#pragma unroll
      for (int cc = 0; cc < 4; ++cc) {
        bf16x8 pA = *(const bf16x8*)(&pw[l16 * 128 + (((cc * 4 + quad) ^ swq) << 3)]);
#pragma unroll
        for (int nt = 0; nt < 4; ++nt) {
          bf16x8 vB = *(const bf16x8*)(&sV[(nt * 16 + l16) * 128 +
                                           (((cc * 4 + quad) ^ swq) << 3)]);
          OA[nt] = __builtin_amdgcn_mfma_f32_16x16x32_bf16(pA, vB, OA[nt], 0, 0, 0);
        }
      }
    }
  }

  // ---- epilogue
  float invA[4], invB[4];
#pragma unroll
  for (int r = 0; r < 4; ++r) {
    float pa = psA[r], pb = psB[r];
    pa += __shfl_xor(pa, 1); pb += __shfl_xor(pb, 1);
    pa += __shfl_xor(pa, 2); pb += __shfl_xor(pb, 2);
    pa += __shfl_xor(pa, 4); pb += __shfl_xor(pb, 4);
    pa += __shfl_xor(pa, 8); pb += __shfl_xor(pb, 8);
    invA[r] = 1.0f / pa;
    invB[r] = 1.0f / pb;
  }
#pragma unroll
  for (int nt = 0; nt < 4; ++nt) {
#pragma unroll
    for (int r = 0; r < 4; ++r) {
      const int qA = qbA + wave * 16 + quad * 4 + r;
      const int qB = qbB + wave * 16 + quad * 4 + r;
      Aout[((size_t)b * 1024 + qA) * 1024 + h * 64 + nt * 16 + l16] =
          (__bf16)(OA[nt][r] * invA[r]);
      Aout[((size_t)b * 1024 + qB) * 1024 + h * 64 + nt * 16 + l16] =
          (__bf16)(OB[nt][r] * invB[r]);
    }
  }
}

// ---------------- launch ----------------
extern "C" void kernel_launch(void* const* d_in, const int* in_sizes, int n_in,
                              void* d_out, int out_size, void* d_ws,
                              size_t ws_size, hipStream_t stream) {
  const float* x      = (const float*)d_in[0];
  const float* w_attn = (const float*)d_in[1];
  const float* b_attn = (const float*)d_in[2];
  const float* w_proj = (const float*)d_in[3];
  const float* b_proj = (const float*)d_in[4];
  float* out = (float*)d_out;

  char* ws = (char*)d_ws;
  __bf16* WT_attn = (__bf16*)(ws);                  //  6 MB
  __bf16* WT_proj = (__bf16*)(ws + 6291456);        //  2 MB
  __bf16* Xb      = (__bf16*)(ws + 8388608);        //  8 MB (reused as VT)
  __bf16* Qp      = (__bf16*)(ws + 16777216);       //  8 MB [bh][s][64]
  __bf16* Kp      = (__bf16*)(ws + 25165824);       //  8 MB [bh][s][64]
  __bf16* Vr      = (__bf16*)(ws + 33554432);       //  8 MB [s_glob][1024]
  __bf16* Aattn   = (__bf16*)(ws + 41943040);       //  8 MB (end 50 MB)
  __bf16* VT      = Xb;  // x-as-bf16 dead after GEMM1

  prep<<<5120, 256, 0, stream>>>(x, w_attn, w_proj, Xb, WT_attn, WT_proj);
  gemm_qkv<<<dim3(24, 32), 256, 0, stream>>>(Xb, WT_attn, b_attn, Qp, Kp, Vr);
  transpose_v<<<1024, 256, 0, stream>>>(Vr, VT);
  attn_mfma<<<512, 256, 0, stream>>>(Qp, Kp, VT, Aattn);
  gemm_out<<<dim3(8, 32), 256, 0, stream>>>(Aattn, WT_proj, b_proj, out);
}